// Round 4
// baseline (325.155 us; speedup 1.0000x reference)
//
#include <hip/hip_runtime.h>

// RRSVM: per (b,c,h,w) take 3x3 zero-padded window, stable-sort descending,
// out = sum_r v_sorted[r] * s[c,r]; also emit argsort indices (rank order),
// written as float-encoded ints (harness reads whole d_out as float32).
//
// R4: 4 pixels/thread (quad shares a row; 3 rows x 6 cols = 3 float4 + 6
// scalar loads for 4 sorts). Each thread owns 36 consecutive index floats
// -> 9 aligned float4 register-direct stores; NO LDS, NO barrier. Relies on
// L2 write-combining to merge the 144B-stride lane pattern into full lines.

#define B_ 16
#define C_ 128
#define H_ 56
#define W_ 56
#define NPIX (B_*C_*H_*W_)   // 6422528
#define BLK 256
#define PXT 4                // pixels per thread

typedef float v4f __attribute__((ext_vector_type(4)));

// Stable descending sort: 9-round odd-even transposition, strict adjacent
// compare (equal keys never swap => smaller original index first, matching
// jnp.argsort(-p) stability). Verified absmax==0 in R1/R3.
__device__ __forceinline__ void sort9(float v[9], float id[9]) {
    #pragma unroll
    for (int rnd = 0; rnd < 9; ++rnd) {
        #pragma unroll
        for (int i = (rnd & 1); i + 1 < 9; i += 2) {
            float vi = v[i], vj = v[i + 1];
            float ii = id[i], ij = id[i + 1];
            bool sw = vj > vi;
            v[i]      = sw ? vj : vi;  v[i + 1]  = sw ? vi : vj;
            id[i]     = sw ? ij : ii;  id[i + 1] = sw ? ii : ij;
        }
    }
}

__global__ __launch_bounds__(BLK) void rrsvm_kernel(
    const float* __restrict__ x, const float* __restrict__ s,
    float* __restrict__ out, float* __restrict__ idxout)
{
    const int gtid = blockIdx.x * BLK + threadIdx.x;   // 0..NPIX/4-1
    const int pix0 = gtid * PXT;        // 16B-aligned pixel quad, same row
    const int w0   = pix0 % W_;         // in {0,4,...,52}
    const int t    = pix0 / W_;
    const int h    = t % H_;
    const int bc   = t / H_;            // b*C + c
    const int c    = bc & (C_ - 1);

    // ---- per-channel rank weights ----
    const float* sp = s + c * 9;
    float sw9[9];
    #pragma unroll
    for (int r = 0; r < 9; ++r) sw9[r] = sp[r];

    // ---- gather 3 rows x 6 cols: float4 middle + 2 clamped edge scalars ----
    const float* img = x + (size_t)bc * (H_ * W_);
    const int r0 = (h > 0)      ? h - 1 : 0;
    const int r2 = (h < H_ - 1) ? h + 1 : H_ - 1;
    const int cl = (w0 > 0)        ? w0 - 1 : 0;       // left edge col
    const int cr = (w0 < W_ - PXT) ? w0 + 4 : W_ - 1;  // right edge col
    const float* p0 = img + r0 * W_;
    const float* p1 = img + h  * W_;
    const float* p2 = img + r2 * W_;

    float T[3][6];
    {
        v4f m0 = *(const v4f*)(p0 + w0);
        v4f m1 = *(const v4f*)(p1 + w0);
        v4f m2 = *(const v4f*)(p2 + w0);
        T[0][0] = p0[cl]; T[0][1] = m0.x; T[0][2] = m0.y; T[0][3] = m0.z; T[0][4] = m0.w; T[0][5] = p0[cr];
        T[1][0] = p1[cl]; T[1][1] = m1.x; T[1][2] = m1.y; T[1][3] = m1.z; T[1][4] = m1.w; T[1][5] = p1[cr];
        T[2][0] = p2[cl]; T[2][1] = m2.x; T[2][2] = m2.y; T[2][3] = m2.z; T[2][4] = m2.w; T[2][5] = p2[cr];
    }

    // ---- zero-pad via selects ----
    const bool rv0 = (h > 0), rv2 = (h < H_ - 1);
    const bool cvL = (w0 > 0), cvR = (w0 < W_ - PXT);
    #pragma unroll
    for (int j = 0; j < 6; ++j) {
        T[0][j] = rv0 ? T[0][j] : 0.0f;
        T[2][j] = rv2 ? T[2][j] : 0.0f;
    }
    T[0][0] = cvL ? T[0][0] : 0.0f;
    T[1][0] = cvL ? T[1][0] : 0.0f;
    T[2][0] = cvL ? T[2][0] : 0.0f;
    T[0][5] = cvR ? T[0][5] : 0.0f;
    T[1][5] = cvR ? T[1][5] : 0.0f;
    T[2][5] = cvR ? T[2][5] : 0.0f;

    float idxf[36];
    v4f o;
    float oacc[4];

    #pragma unroll
    for (int j = 0; j < PXT; ++j) {
        float v[9]  = { T[0][j], T[0][j+1], T[0][j+2],
                        T[1][j], T[1][j+1], T[1][j+2],
                        T[2][j], T[2][j+1], T[2][j+2] };
        float id[9] = { 0, 1, 2, 3, 4, 5, 6, 7, 8 };
        sort9(v, id);
        float acc = 0.0f;
        #pragma unroll
        for (int r = 0; r < 9; ++r) acc = fmaf(v[r], sw9[r], acc);
        oacc[j] = acc;
        #pragma unroll
        for (int r = 0; r < 9; ++r) idxf[j * 9 + r] = id[r];
    }
    o.x = oacc[0]; o.y = oacc[1]; o.z = oacc[2]; o.w = oacc[3];

    // ---- stores: out float4 + 9 register-direct float4 idx stores ----
    *(v4f*)(out + pix0) = o;

    v4f* dst = (v4f*)(idxout + (size_t)gtid * 36);
    const v4f* srcv = (const v4f*)idxf;
    #pragma unroll
    for (int k = 0; k < 9; ++k)
        dst[k] = srcv[k];
}

extern "C" void kernel_launch(void* const* d_in, const int* in_sizes, int n_in,
                              void* d_out, int out_size, void* d_ws, size_t ws_size,
                              hipStream_t stream) {
    const float* x = (const float*)d_in[0];   // [16,128,56,56]
    const float* s = (const float*)d_in[1];   // [128,3,3]
    float* out    = (float*)d_out;            // first NPIX floats
    float* idxout = out + NPIX;               // then NPIX*9 float-encoded ints

    const int nblocks = NPIX / (BLK * PXT);   // 6272
    rrsvm_kernel<<<nblocks, BLK, 0, stream>>>(x, s, out, idxout);
}

// Round 5
// 291.059 us; speedup vs baseline: 1.1171x; 1.1171x over previous
//
#include <hip/hip_runtime.h>

// RRSVM: per (b,c,h,w) take 3x3 zero-padded window, stable-sort descending,
// out = sum_r v_sorted[r] * s[c,r]; also emit argsort indices (rank order),
// written as float-encoded ints (harness reads whole d_out as float32).
//
// R5 = R4 gather (4 px/thread, 3 float4 + 6 scalar loads) + R3 store path
// (LDS-staged, lane-contiguous nontemporal float4 writeback). R4 proved
// register-direct strided stores don't merge; R1/R3 proved LDS staging works.
// Goal: cut VMEM instruction count ~2x vs R3 (56M -> 30M) under the
// per-CU address-processing cap.

#define B_ 16
#define C_ 128
#define H_ 56
#define W_ 56
#define NPIX (B_*C_*H_*W_)   // 6422528
#define BLK 256
#define PXT 4                // pixels per thread (quad shares a row)
#define PXB (BLK * PXT)      // 1024 pixels per block

typedef float v4f __attribute__((ext_vector_type(4)));

// Stable descending sort: 9-round odd-even transposition, strict adjacent
// compare (equal keys never swap => smaller original index first, matching
// jnp.argsort(-p) stability). Verified absmax==0 in R1/R3/R4.
__device__ __forceinline__ void sort9(float v[9], float id[9]) {
    #pragma unroll
    for (int rnd = 0; rnd < 9; ++rnd) {
        #pragma unroll
        for (int i = (rnd & 1); i + 1 < 9; i += 2) {
            float vi = v[i], vj = v[i + 1];
            float ii = id[i], ij = id[i + 1];
            bool sw = vj > vi;
            v[i]      = sw ? vj : vi;  v[i + 1]  = sw ? vi : vj;
            id[i]     = sw ? ij : ii;  id[i + 1] = sw ? ii : ij;
        }
    }
}

__global__ __launch_bounds__(BLK) void rrsvm_kernel(
    const float* __restrict__ x, const float* __restrict__ s,
    float* __restrict__ out, float* __restrict__ idxout)
{
    __shared__ float lds[PXB * 9];   // 36864 B index staging tile

    const int tid  = threadIdx.x;
    const int gtid = blockIdx.x * BLK + tid;
    const int pix0 = gtid * PXT;        // 16B-aligned pixel quad, same row
    const int w0   = pix0 % W_;         // in {0,4,...,52}
    const int t    = pix0 / W_;
    const int h    = t % H_;
    const int bc   = t / H_;            // b*C + c
    const int c    = bc & (C_ - 1);

    // ---- per-channel rank weights ----
    const float* sp = s + c * 9;
    float sw9[9];
    #pragma unroll
    for (int r = 0; r < 9; ++r) sw9[r] = sp[r];

    // ---- gather 3 rows x 6 cols: float4 middle + 2 clamped edge scalars ----
    const float* img = x + (size_t)bc * (H_ * W_);
    const int r0 = (h > 0)      ? h - 1 : 0;
    const int r2 = (h < H_ - 1) ? h + 1 : H_ - 1;
    const int cl = (w0 > 0)        ? w0 - 1 : 0;       // left edge col
    const int cr = (w0 < W_ - PXT) ? w0 + 4 : W_ - 1;  // right edge col
    const float* p0 = img + r0 * W_;
    const float* p1 = img + h  * W_;
    const float* p2 = img + r2 * W_;

    float T[3][6];
    {
        v4f m0 = *(const v4f*)(p0 + w0);
        v4f m1 = *(const v4f*)(p1 + w0);
        v4f m2 = *(const v4f*)(p2 + w0);
        T[0][0] = p0[cl]; T[0][1] = m0.x; T[0][2] = m0.y; T[0][3] = m0.z; T[0][4] = m0.w; T[0][5] = p0[cr];
        T[1][0] = p1[cl]; T[1][1] = m1.x; T[1][2] = m1.y; T[1][3] = m1.z; T[1][4] = m1.w; T[1][5] = p1[cr];
        T[2][0] = p2[cl]; T[2][1] = m2.x; T[2][2] = m2.y; T[2][3] = m2.z; T[2][4] = m2.w; T[2][5] = p2[cr];
    }

    // ---- zero-pad via selects ----
    const bool rv0 = (h > 0), rv2 = (h < H_ - 1);
    const bool cvL = (w0 > 0), cvR = (w0 < W_ - PXT);
    #pragma unroll
    for (int j = 0; j < 6; ++j) {
        T[0][j] = rv0 ? T[0][j] : 0.0f;
        T[2][j] = rv2 ? T[2][j] : 0.0f;
    }
    T[0][0] = cvL ? T[0][0] : 0.0f;
    T[1][0] = cvL ? T[1][0] : 0.0f;
    T[2][0] = cvL ? T[2][0] : 0.0f;
    T[0][5] = cvR ? T[0][5] : 0.0f;
    T[1][5] = cvR ? T[1][5] : 0.0f;
    T[2][5] = cvR ? T[2][5] : 0.0f;

    // ---- 4 sorts; assemble 36 index floats as 9 v4f (all-constant lanes) ----
    v4f q[9];
    float oacc[4];
    #pragma unroll
    for (int j = 0; j < PXT; ++j) {
        float v[9]  = { T[0][j], T[0][j+1], T[0][j+2],
                        T[1][j], T[1][j+1], T[1][j+2],
                        T[2][j], T[2][j+1], T[2][j+2] };
        float id[9] = { 0, 1, 2, 3, 4, 5, 6, 7, 8 };
        sort9(v, id);
        float acc = 0.0f;
        #pragma unroll
        for (int r = 0; r < 9; ++r) acc = fmaf(v[r], sw9[r], acc);
        oacc[j] = acc;
        #pragma unroll
        for (int r = 0; r < 9; ++r) {
            const int f = j * 9 + r;       // compile-time constant
            q[f >> 2][f & 3] = id[r];
        }
    }
    v4f o; o.x = oacc[0]; o.y = oacc[1]; o.z = oacc[2]; o.w = oacc[3];

    // ---- out store: coalesced float4 ----
    __builtin_nontemporal_store(o, (v4f*)(out + pix0));

    // ---- stage indices: 9 ds_write_b128, start bank 4*tid%32 (even tiling,
    //      conflict-free), then lane-contiguous NT float4 writeback ----
    v4f* lw = (v4f*)(lds + (size_t)tid * 36);   // 144B stride, 16B aligned
    #pragma unroll
    for (int k = 0; k < 9; ++k)
        lw[k] = q[k];

    __syncthreads();

    // block region: 1024*9 = 9216 floats = 2304 float4 = 9 * 256
    v4f* dst = (v4f*)(idxout + (size_t)blockIdx.x * (PXB * 9));
    const v4f* src = (const v4f*)lds;
    #pragma unroll
    for (int k = 0; k < 9; ++k)
        __builtin_nontemporal_store(src[tid + k * 256], dst + tid + k * 256);
}

extern "C" void kernel_launch(void* const* d_in, const int* in_sizes, int n_in,
                              void* d_out, int out_size, void* d_ws, size_t ws_size,
                              hipStream_t stream) {
    const float* x = (const float*)d_in[0];   // [16,128,56,56]
    const float* s = (const float*)d_in[1];   // [128,3,3]
    float* out    = (float*)d_out;            // first NPIX floats
    float* idxout = out + NPIX;               // then NPIX*9 float-encoded ints

    const int nblocks = NPIX / PXB;           // 6272
    rrsvm_kernel<<<nblocks, BLK, 0, stream>>>(x, s, out, idxout);
}